// Round 1
// 259.247 us; speedup vs baseline: 1.0385x; 1.0385x over previous
//
#include <hip/hip_runtime.h>
#include <cstdint>
#include <cstddef>

#define MDIM 4096   // batch
#define NDIM 4096   // out features
#define KDIM 4096   // in features

typedef _Float16 half8   __attribute__((ext_vector_type(8)));
typedef float    floatx4 __attribute__((ext_vector_type(4)));

// Hamilton product tables: out_comp = sum_c sign[comp][c] * (x_c @ W_{comp^c}^T)
__device__ __constant__ int   d_qtab[16] = {0,1,2,3,  1,0,3,2,  2,3,0,1,  3,2,1,0};
__device__ __constant__ float d_stab[16] = {1.f,-1.f,-1.f,-1.f,
                                            1.f, 1.f, 1.f,-1.f,
                                            1.f,-1.f, 1.f, 1.f,
                                            1.f, 1.f,-1.f, 1.f};

// ---------------- fused pre-pass: cast x -> fp16, cast W -> fp16 ----------------
__global__ void prepass_kernel(const float* __restrict__ x,
                               const float* __restrict__ W0, const float* __restrict__ W1,
                               const float* __restrict__ W2, const float* __restrict__ W3,
                               _Float16* __restrict__ xh, _Float16* __restrict__ Wh) {
    int b = blockIdx.x;
    if (b < 8192) {
        int idx = b * 256 + threadIdx.x;               // 0 .. 2M-1
        const float4* src = (const float4*)x + (size_t)idx * 2;
        float4 a = src[0], v = src[1];
        half8 h = {(_Float16)a.x, (_Float16)a.y, (_Float16)a.z, (_Float16)a.w,
                   (_Float16)v.x, (_Float16)v.y, (_Float16)v.z, (_Float16)v.w};
        ((half8*)xh)[idx] = h;
    } else {
        int idx = (b - 8192) * 256 + threadIdx.x;      // 0 .. 512K-1
        int e = idx << 3;                               // 0 .. 4M-1
        int m = e >> 20;
        int off = e & ((1 << 20) - 1);
        const float* Ws[4] = {W0, W1, W2, W3};
        const float* src = Ws[m] + off;
        float4 a = *(const float4*)src;
        float4 v = *(const float4*)(src + 4);
        half8 h = {(_Float16)a.x, (_Float16)a.y, (_Float16)a.z, (_Float16)a.w,
                   (_Float16)v.x, (_Float16)v.y, (_Float16)v.z, (_Float16)v.w};
        *(half8*)(Wh + ((size_t)m << 20) + off) = h;
    }
}

// ---------------- MFMA GEMM: 256x256 tile, BK=64, 8 waves, 8-phase pipeline ----
// T3+T4+T5 port of the m201 schedule. 2 LDS K-tile buffers (128 KiB total).
// A buffer split into quadrant-aligned halves:
//   Ag0 = global rows {0..63} U {128..191}   (read by phases 1,2 of its tile)
//   Ag1 = global rows {64..127} U {192..255} (read by phases 3,4)
// B buffer split by N: Bn0 = rows 0..127, Bn1 = 128..255 (both read ph1,2;
// kh-frags cached in regs and reused at ph3,4).
// Staging schedule per tile t (cur=t&1, nxt=cur^1):
//   ph1: Bn1(t+1)->nxt   ph2: Ag1(t+1)->nxt   ph3: Ag0(t+2)->cur   ph4: Bn0(t+2)->cur
//   (ph3/ph4 write regions of cur freed at ph2 -- barrier-separated, race-free)
// Counted waits (2 loads per half-tile, per wave):
//   ph2: vmcnt(8)  -- lands Ag1(t)  [issued t-1 ph2], needed ph3
//   ph4: vmcnt(6)  -- lands Ag0/Bn0/Bn1(t+1), leaves 3 half-tiles in flight
// Never vmcnt(0) in the loop. Tail: t1/t2 clamped to 63 (re-stage same data into
// dead regions) so the vmcnt ledger is identical every iteration.
// LDS geometry per region: rows of 64 halves (128 B), slot = chunk ^ (row&7)
// (carried over from the R7-proven layout; measured 0 bank conflicts).

__device__ __forceinline__ void gload_lds16(const _Float16* g, _Float16* l) {
    __builtin_amdgcn_global_load_lds(
        (const __attribute__((address_space(1))) unsigned int*)g,
        (__attribute__((address_space(3))) unsigned int*)l,
        16, 0, 0);
}

#define BAR __builtin_amdgcn_s_barrier()
#define WAITLGKM do { asm volatile("s_waitcnt lgkmcnt(0)" ::: "memory"); \
                      __builtin_amdgcn_sched_barrier(0); } while (0)
#define WAITVM(N) asm volatile("s_waitcnt vmcnt(" #N ")" ::: "memory")

// stage A quadrant-half g of K-tile tt into buffer buf (2 x 64 rows)
#define STA(g, tt, buf) { \
    const _Float16* _s = Abase + (size_t)((g) * 64) * KDIM + (tt) * 64; \
    _Float16* _d = AsSt + (buf) * 16384 + (g) * 8192; \
    gload_lds16(_s, _d); \
    gload_lds16(_s + (size_t)128 * KDIM, _d + 4096); }

// stage B n-half h of K-tile tt into buffer buf
#define STB(h, tt, buf) { \
    const int _sg = (tt) >> 4; \
    const _Float16* _s = Bbase + ((size_t)(comp ^ _sg) << 20) \
                       + (size_t)((h) * 128) * 1024 + ((tt) & 15) * 64; \
    _Float16* _d = BsSt + (buf) * 16384 + (h) * 8192; \
    gload_lds16(_s, _d); \
    gload_lds16(_s + 64 * 1024, _d + 4096); }

#define RDA(g, SL) { \
    const _Float16* _p = Acur + (g) * 8192 + arow + (SL); \
    af[0] = *(const half8*)(_p); \
    af[1] = *(const half8*)(_p + 1024); \
    af[2] = *(const half8*)(_p + 2048); \
    af[3] = *(const half8*)(_p + 3072); }

#define RDB(BQ, SL) { \
    const _Float16* _p = Bcur + bnh * 8192 + brow + (SL); \
    BQ[0] = *(const half8*)(_p); \
    BQ[1] = *(const half8*)(_p + 1024); \
    BQ[2] = *(const half8*)(_p + 2048); \
    BQ[3] = *(const half8*)(_p + 3072); \
    if (bneg) { BQ[0] = -BQ[0]; BQ[1] = -BQ[1]; BQ[2] = -BQ[2]; BQ[3] = -BQ[3]; } }

#define MFMA16(IB, BQ) \
    _Pragma("unroll") \
    for (int _i = 0; _i < 4; _i++) \
      _Pragma("unroll") \
      for (int _j = 0; _j < 4; _j++) \
        acc[(IB) + _i][_j] = __builtin_amdgcn_mfma_f32_16x16x32_f16( \
            af[_i], BQ[_j], acc[(IB) + _i][_j], 0, 0, 0);

__global__ __launch_bounds__(512, 2) void gemm_kernel(
        const _Float16* __restrict__ A,      // [4096,4096] fp16
        const _Float16* __restrict__ Wh,     // [4][1024][1024] fp16
        const float* __restrict__ b0, const float* __restrict__ b1,
        const float* __restrict__ b2, const float* __restrict__ b3,
        float* __restrict__ C) {
    __shared__ _Float16 lds[65536];          // 128 KiB
    _Float16* As = lds;                      // [buf][g][8192]
    _Float16* Bs = lds + 32768;              // [buf][nh][8192]

    const int tid  = threadIdx.x;
    const int lane = tid & 63;
    const int wave = tid >> 6;               // 0..7
    const int wmh  = wave >> 2;              // M-half of 256-row tile (0/1)
    const int wn   = (wave & 3) * 64;        // N offset within 256-col tile
    const int bnh  = wn >> 7;                // which B n-half this wave reads
    const int broff = (wn & 64) * 64;        // row base (halves) within B region

    // bijective XCD swizzle (nwg=256 divisible by 8): each XCD gets 2 full
    // bm-rows (all 16 bn) -> A panels L2-local per XCD.
    const int wg = ((blockIdx.x & 7) << 5) | (blockIdx.x >> 3);
    const int bm = wg >> 4, bn = wg & 15;
    const int m0 = bm << 8;
    const int n0 = bn << 8;
    const int comp = bn >> 2;                // output quaternion component
    const int n0q  = n0 & 1023;

    // staging geometry: 8 threads/row, 16B chunks, slot s holds chunk s^(row&7)
    const int lrow = tid >> 3;               // 0..63
    const int gch  = (tid & 7) ^ (lrow & 7);
    const _Float16* Abase = A  + (size_t)(m0  + lrow) * KDIM + gch * 8;
    const _Float16* Bbase = Wh + (size_t)(n0q + lrow) * 1024 + gch * 8;
    _Float16* AsSt = As + tid * 8;
    _Float16* BsSt = Bs + tid * 8;

    // fragment geometry (16x16x32): m/n = fr, k = kh*32 + qf*8 + j
    const int fr  = lane & 15;
    const int qf  = lane >> 4;
    const int fsw = fr & 7;
    const int sl0 = ((0 + qf) ^ fsw) * 8;    // kh=0 slot (halves)
    const int sl1 = ((4 + qf) ^ fsw) * 8;    // kh=1 slot
    const int arow = wmh * 4096 + fr * 64;   // within A quadrant region
    const int brow = broff + fr * 64;        // within B n-half region

    // signs: one negated segment per comp + global flip (comp0 only)
    const int negseg = (comp == 0) ? 0 : (comp == 1) ? 3 : (comp == 2) ? 1 : 2;
    const float flip = (comp == 0) ? -1.f : 1.f;

    floatx4 acc[8][4];
#pragma unroll
    for (int i = 0; i < 8; i++)
#pragma unroll
        for (int j = 0; j < 4; j++)
            acc[i][j] = (floatx4){0.f, 0.f, 0.f, 0.f};

    // ---- prologue: tile0 fully + Ag0/Bn0 of tile1; leave 3 half-tiles in flight
    STA(0, 0, 0); STB(0, 0, 0); STB(1, 0, 0); STA(1, 0, 0);
    STA(0, 1, 1); STB(0, 1, 1);
    WAITVM(6);                               // lands Ag0/Bn0/Bn1 of tile 0
    BAR;

    for (int tt = 0; tt < 64; ++tt) {
        const int cur = tt & 1, nxt = cur ^ 1;
        const bool bneg = ((tt >> 4) == negseg);
        const _Float16* Acur = As + cur * 16384;
        const _Float16* Bcur = Bs + cur * 16384;
        const int t1 = (tt >= 63) ? 63 : tt + 1;
        const int t2 = (tt >= 62) ? 63 : tt + 2;
        half8 af[4], bf0[4], bf1[4];

        // ---- phase 1: quad(g0,kh0), load+scale bf0; prefetch Bn1(t+1)
        RDA(0, sl0); RDB(bf0, sl0);
        STB(1, t1, nxt);
        BAR; WAITLGKM;
        __builtin_amdgcn_s_setprio(1);
        MFMA16(0, bf0);
        __builtin_amdgcn_s_setprio(0);
        BAR;

        // ---- phase 2: quad(g0,kh1), load+scale bf1; prefetch Ag1(t+1)
        RDA(0, sl1); RDB(bf1, sl1);
        STA(1, t1, nxt);
        BAR; WAITLGKM;
        __builtin_amdgcn_s_setprio(1);
        MFMA16(0, bf1);
        __builtin_amdgcn_s_setprio(0);
        WAITVM(8);                           // lands Ag1(tt) for phase 3
        BAR;

        // ---- phase 3: quad(g1,kh0), reuse bf0; prefetch Ag0(t+2) into cur
        RDA(1, sl0);
        STA(0, t2, cur);                     // region freed at ph2
        BAR; WAITLGKM;
        __builtin_amdgcn_s_setprio(1);
        MFMA16(4, bf0);
        __builtin_amdgcn_s_setprio(0);
        BAR;

        // ---- phase 4: quad(g1,kh1), reuse bf1; prefetch Bn0(t+2) into cur
        RDA(1, sl1);
        STB(0, t2, cur);                     // region freed at ph2
        BAR; WAITLGKM;
        __builtin_amdgcn_s_setprio(1);
        MFMA16(4, bf1);
        __builtin_amdgcn_s_setprio(0);
        WAITVM(6);                           // lands tile t+1's ph1/ph2 needs
        BAR;
    }

    WAITVM(0);   // drain tail DMAs before LDS teardown

    // Epilogue: D[row][col], col = lane&15, row = (lane>>4)*4 + r  [m89 layout]
    const int col   = lane & 15;
    const int rquad = (lane >> 4) * 4;
    const int wm    = wmh * 128;
    const float* bsp[4] = {b0, b1, b2, b3};
#pragma unroll
    for (int j = 0; j < 4; j++) {
        const int gn = n0 + wn + j * 16 + col;
        const int o  = gn & 1023;
        float bv = 0.f;
#pragma unroll
        for (int c = 0; c < 4; c++)
            bv += d_stab[comp * 4 + c] * bsp[comp ^ c][o];
#pragma unroll
        for (int i = 0; i < 8; i++) {
            const int gmb = m0 + wm + i * 16 + rquad;
#pragma unroll
            for (int r = 0; r < 4; r++)
                C[(size_t)(gmb + r) * NDIM + gn] = flip * acc[i][j][r] + bv;
        }
    }
}

// ---------------- fp32 fallback (only if ws too small) ----------------
__global__ void fallback_kernel(const float* __restrict__ x,
                                const float* __restrict__ W0, const float* __restrict__ W1,
                                const float* __restrict__ W2, const float* __restrict__ W3,
                                const float* __restrict__ b0, const float* __restrict__ b1,
                                const float* __restrict__ b2, const float* __restrict__ b3,
                                float* __restrict__ out) {
    int idx = blockIdx.x * 256 + threadIdx.x;   // 16M outputs
    int m = idx >> 12, n = idx & 4095;
    int comp = n >> 10, o = n & 1023;
    const float* Ws[4] = {W0, W1, W2, W3};
    const float* bs[4] = {b0, b1, b2, b3};
    float acc = 0.f;
    for (int c = 0; c < 4; c++) {
        int t = comp * 4 + c;
        const float* wr = Ws[d_qtab[t]] + (size_t)o * 1024;
        const float* xr = x + (size_t)m * 4096 + c * 1024;
        float s = d_stab[t];
        float dot = 0.f;
        for (int i = 0; i < 1024; i += 4) {
            float4 wv = *(const float4*)(wr + i);
            float4 xv = *(const float4*)(xr + i);
            dot += wv.x * xv.x + wv.y * xv.y + wv.z * xv.z + wv.w * xv.w;
        }
        acc += s * dot + s * bs[d_qtab[t]][o];
    }
    out[idx] = acc;
}

// ---------------- launch ----------------
extern "C" void kernel_launch(void* const* d_in, const int* in_sizes, int n_in,
                              void* d_out, int out_size, void* d_ws, size_t ws_size,
                              hipStream_t stream) {
    const float* x = (const float*)d_in[0];
    const float* W[4];
    const float* b[4];
    int wi = 0, bi = 0;
    for (int i = 1; i < n_in && i < 9; i++) {
        if (in_sizes[i] > 4096) { if (wi < 4) W[wi++] = (const float*)d_in[i]; }
        else                    { if (bi < 4) b[bi++] = (const float*)d_in[i]; }
    }
    float* out = (float*)d_out;

    const size_t xh_elems = (size_t)MDIM * KDIM;        // 16M fp16 = 32 MB
    const size_t wh_elems = (size_t)4 * 1024 * 1024;    // 4M fp16 = 8 MB
    const size_t needed = (xh_elems + wh_elems) * 2;

    if (ws_size < needed) {
        fallback_kernel<<<(MDIM * NDIM) / 256, 256, 0, stream>>>(
            x, W[0], W[1], W[2], W[3], b[0], b[1], b[2], b[3], out);
        return;
    }

    _Float16* xh = (_Float16*)d_ws;
    _Float16* Wh = xh + xh_elems;

    prepass_kernel<<<8192 + 2048, 256, 0, stream>>>(x, W[0], W[1], W[2], W[3], xh, Wh);
    gemm_kernel<<<(MDIM / 256) * (NDIM / 256), 512, 0, stream>>>(
        xh, Wh, b[0], b[1], b[2], b[3], out);
}

// Round 3
// 254.145 us; speedup vs baseline: 1.0593x; 1.0201x over previous
//
#include <hip/hip_runtime.h>
#include <cstdint>
#include <cstddef>

#define MDIM 4096   // batch
#define NDIM 4096   // out features
#define KDIM 4096   // in features

typedef _Float16 half8   __attribute__((ext_vector_type(8)));
typedef float    floatx4 __attribute__((ext_vector_type(4)));

// Hamilton product tables: out_comp = sum_c sign[comp][c] * (x_c @ W_{comp^c}^T)
__device__ __constant__ int   d_qtab[16] = {0,1,2,3,  1,0,3,2,  2,3,0,1,  3,2,1,0};
__device__ __constant__ float d_stab[16] = {1.f,-1.f,-1.f,-1.f,
                                            1.f, 1.f, 1.f,-1.f,
                                            1.f,-1.f, 1.f, 1.f,
                                            1.f, 1.f,-1.f, 1.f};

// ---------------- fused pre-pass: cast x -> fp16, cast W -> fp16 ----------------
__global__ void prepass_kernel(const float* __restrict__ x,
                               const float* __restrict__ W0, const float* __restrict__ W1,
                               const float* __restrict__ W2, const float* __restrict__ W3,
                               _Float16* __restrict__ xh, _Float16* __restrict__ Wh) {
    int b = blockIdx.x;
    if (b < 8192) {
        int idx = b * 256 + threadIdx.x;               // 0 .. 2M-1
        const float4* src = (const float4*)x + (size_t)idx * 2;
        float4 a = src[0], v = src[1];
        half8 h = {(_Float16)a.x, (_Float16)a.y, (_Float16)a.z, (_Float16)a.w,
                   (_Float16)v.x, (_Float16)v.y, (_Float16)v.z, (_Float16)v.w};
        ((half8*)xh)[idx] = h;
    } else {
        int idx = (b - 8192) * 256 + threadIdx.x;      // 0 .. 512K-1
        int e = idx << 3;                               // 0 .. 4M-1
        int m = e >> 20;
        int off = e & ((1 << 20) - 1);
        const float* Ws[4] = {W0, W1, W2, W3};
        const float* src = Ws[m] + off;
        float4 a = *(const float4*)src;
        float4 v = *(const float4*)(src + 4);
        half8 h = {(_Float16)a.x, (_Float16)a.y, (_Float16)a.z, (_Float16)a.w,
                   (_Float16)v.x, (_Float16)v.y, (_Float16)v.z, (_Float16)v.w};
        *(half8*)(Wh + ((size_t)m << 20) + off) = h;
    }
}

// ---------------- MFMA GEMM: 256x256 tile, BK=64, 8 waves, 4-phase pipeline ----
// R2 change vs R1: the pre-MFMA barrier of each phase is REMOVED. Per-phase is
// now {ds_read; stage-issue; lgkmcnt(0); MFMA; [counted vmcnt]; BAR}. Hazard
// re-derivation: each wave's lgkmcnt(0) precedes its MFMA which precedes the
// phase-end barrier, so by any phase-end barrier ALL waves' reads of the
// regions overwritten in later phases have drained; region-reads follow the
// barrier after the counted WAITVM that landed them. The removed barrier was
// pure lockstep: it serialized {all-waves-LDS-read} -> {all-waves-MFMA},
// capping MfmaUtil at MFMA/(MFMA+LDS) ~= 45% (measured 41%).
//
// Staging schedule per tile t (cur=t&1, nxt=cur^1):
//   ph1: Bn1(t+1)->nxt   ph2: Ag1(t+1)->nxt   ph3: Ag0(t+2)->cur   ph4: Bn0(t+2)->cur
// Counted waits (2 loads per half-tile, per wave):
//   ph2: vmcnt(8)  -- lands Ag1(t)  [issued t-1 ph2], needed ph3
//   ph4: vmcnt(6)  -- lands Ag0/Bn0/Bn1(t+1), leaves 3 half-tiles in flight
// Never vmcnt(0) in the loop. Tail: t1/t2 clamped to 63 (re-stage same data into
// dead regions) so the vmcnt ledger is identical every iteration.
// LDS geometry per region: rows of 64 halves (128 B), slot = chunk ^ (row&7)
// (R7-proven layout; measured 0 bank conflicts in R0 and R1).

__device__ __forceinline__ void gload_lds16(const _Float16* g, _Float16* l) {
    __builtin_amdgcn_global_load_lds(
        (const __attribute__((address_space(1))) unsigned int*)g,
        (__attribute__((address_space(3))) unsigned int*)l,
        16, 0, 0);
}

#define BAR __builtin_amdgcn_s_barrier()
#define WAITLGKM do { asm volatile("s_waitcnt lgkmcnt(0)" ::: "memory"); \
                      __builtin_amdgcn_sched_barrier(0); } while (0)
#define WAITVM(N) asm volatile("s_waitcnt vmcnt(" #N ")" ::: "memory")

// stage A quadrant-half g of K-tile tt into buffer buf (2 x 64 rows)
#define STA(g, tt, buf) { \
    const _Float16* _s = Abase + (size_t)((g) * 64) * KDIM + (tt) * 64; \
    _Float16* _d = AsSt + (buf) * 16384 + (g) * 8192; \
    gload_lds16(_s, _d); \
    gload_lds16(_s + (size_t)128 * KDIM, _d + 4096); }

// stage B n-half h of K-tile tt into buffer buf
#define STB(h, tt, buf) { \
    const int _sg = (tt) >> 4; \
    const _Float16* _s = Bbase + ((size_t)(comp ^ _sg) << 20) \
                       + (size_t)((h) * 128) * 1024 + ((tt) & 15) * 64; \
    _Float16* _d = BsSt + (buf) * 16384 + (h) * 8192; \
    gload_lds16(_s, _d); \
    gload_lds16(_s + 64 * 1024, _d + 4096); }

#define RDA(g, SL) { \
    const _Float16* _p = Acur + (g) * 8192 + arow + (SL); \
    af[0] = *(const half8*)(_p); \
    af[1] = *(const half8*)(_p + 1024); \
    af[2] = *(const half8*)(_p + 2048); \
    af[3] = *(const half8*)(_p + 3072); }

#define RDB(BQ, SL) { \
    const _Float16* _p = Bcur + bnh * 8192 + brow + (SL); \
    BQ[0] = *(const half8*)(_p); \
    BQ[1] = *(const half8*)(_p + 1024); \
    BQ[2] = *(const half8*)(_p + 2048); \
    BQ[3] = *(const half8*)(_p + 3072); \
    if (bneg) { BQ[0] = -BQ[0]; BQ[1] = -BQ[1]; BQ[2] = -BQ[2]; BQ[3] = -BQ[3]; } }

#define MFMA16(IB, BQ) \
    _Pragma("unroll") \
    for (int _i = 0; _i < 4; _i++) \
      _Pragma("unroll") \
      for (int _j = 0; _j < 4; _j++) \
        acc[(IB) + _i][_j] = __builtin_amdgcn_mfma_f32_16x16x32_f16( \
            af[_i], BQ[_j], acc[(IB) + _i][_j], 0, 0, 0);

__global__ __launch_bounds__(512, 2) void gemm_kernel(
        const _Float16* __restrict__ A,      // [4096,4096] fp16
        const _Float16* __restrict__ Wh,     // [4][1024][1024] fp16
        const float* __restrict__ b0, const float* __restrict__ b1,
        const float* __restrict__ b2, const float* __restrict__ b3,
        float* __restrict__ C) {
    __shared__ _Float16 lds[65536];          // 128 KiB
    _Float16* As = lds;                      // [buf][g][8192]
    _Float16* Bs = lds + 32768;              // [buf][nh][8192]

    const int tid  = threadIdx.x;
    const int lane = tid & 63;
    const int wave = tid >> 6;               // 0..7
    const int wmh  = wave >> 2;              // M-half of 256-row tile (0/1)
    const int wn   = (wave & 3) * 64;        // N offset within 256-col tile
    const int bnh  = wn >> 7;                // which B n-half this wave reads
    const int broff = (wn & 64) * 64;        // row base (halves) within B region

    // bijective XCD swizzle (nwg=256 divisible by 8): each XCD gets 2 full
    // bm-rows (all 16 bn) -> A panels L2-local per XCD.
    const int wg = ((blockIdx.x & 7) << 5) | (blockIdx.x >> 3);
    const int bm = wg >> 4, bn = wg & 15;
    const int m0 = bm << 8;
    const int n0 = bn << 8;
    const int comp = bn >> 2;                // output quaternion component
    const int n0q  = n0 & 1023;

    // staging geometry: 8 threads/row, 16B chunks, slot s holds chunk s^(row&7)
    const int lrow = tid >> 3;               // 0..63
    const int gch  = (tid & 7) ^ (lrow & 7);
    const _Float16* Abase = A  + (size_t)(m0  + lrow) * KDIM + gch * 8;
    const _Float16* Bbase = Wh + (size_t)(n0q + lrow) * 1024 + gch * 8;
    _Float16* AsSt = As + tid * 8;
    _Float16* BsSt = Bs + tid * 8;

    // fragment geometry (16x16x32): m/n = fr, k = kh*32 + qf*8 + j
    const int fr  = lane & 15;
    const int qf  = lane >> 4;
    const int fsw = fr & 7;
    const int sl0 = ((0 + qf) ^ fsw) * 8;    // kh=0 slot (halves)
    const int sl1 = ((4 + qf) ^ fsw) * 8;    // kh=1 slot
    const int arow = wmh * 4096 + fr * 64;   // within A quadrant region
    const int brow = broff + fr * 64;        // within B n-half region

    // signs: one negated segment per comp + global flip (comp0 only)
    const int negseg = (comp == 0) ? 0 : (comp == 1) ? 3 : (comp == 2) ? 1 : 2;
    const float flip = (comp == 0) ? -1.f : 1.f;

    floatx4 acc[8][4];
#pragma unroll
    for (int i = 0; i < 8; i++)
#pragma unroll
        for (int j = 0; j < 4; j++)
            acc[i][j] = (floatx4){0.f, 0.f, 0.f, 0.f};

    // ---- prologue: tile0 fully + Ag0/Bn0 of tile1; leave 3 half-tiles in flight
    STA(0, 0, 0); STB(0, 0, 0); STB(1, 0, 0); STA(1, 0, 0);
    STA(0, 1, 1); STB(0, 1, 1);
    WAITVM(6);                               // lands Ag0/Bn0/Bn1 of tile 0
    BAR;

    for (int tt = 0; tt < 64; ++tt) {
        const int cur = tt & 1, nxt = cur ^ 1;
        const bool bneg = ((tt >> 4) == negseg);
        const _Float16* Acur = As + cur * 16384;
        const _Float16* Bcur = Bs + cur * 16384;
        const int t1 = (tt >= 63) ? 63 : tt + 1;
        const int t2 = (tt >= 62) ? 63 : tt + 2;
        half8 af[4], bf0[4], bf1[4];

        // ---- phase 1: quad(g0,kh0), load+scale bf0; prefetch Bn1(t+1)
        RDA(0, sl0); RDB(bf0, sl0);
        STB(1, t1, nxt);
        WAITLGKM;
        __builtin_amdgcn_s_setprio(1);
        MFMA16(0, bf0);
        __builtin_amdgcn_s_setprio(0);
        BAR;

        // ---- phase 2: quad(g0,kh1), load+scale bf1; prefetch Ag1(t+1)
        RDA(0, sl1); RDB(bf1, sl1);
        STA(1, t1, nxt);
        WAITLGKM;
        __builtin_amdgcn_s_setprio(1);
        MFMA16(0, bf1);
        __builtin_amdgcn_s_setprio(0);
        WAITVM(8);                           // lands Ag1(tt) for phase 3
        BAR;

        // ---- phase 3: quad(g1,kh0), reuse bf0; prefetch Ag0(t+2) into cur
        RDA(1, sl0);
        STA(0, t2, cur);                     // region freed: all reads drained
        WAITLGKM;                            //   before each wave's ph2 MFMA < BAR
        __builtin_amdgcn_s_setprio(1);
        MFMA16(4, bf0);
        __builtin_amdgcn_s_setprio(0);
        BAR;

        // ---- phase 4: quad(g1,kh1), reuse bf1; prefetch Bn0(t+2) into cur
        RDA(1, sl1);
        STB(0, t2, cur);
        WAITLGKM;
        __builtin_amdgcn_s_setprio(1);
        MFMA16(4, bf1);
        __builtin_amdgcn_s_setprio(0);
        WAITVM(6);                           // lands tile t+1's ph1/ph2 needs
        BAR;
    }

    WAITVM(0);   // drain tail DMAs before LDS teardown

    // Epilogue: D[row][col], col = lane&15, row = (lane>>4)*4 + r  [m89 layout]
    const int col   = lane & 15;
    const int rquad = (lane >> 4) * 4;
    const int wm    = wmh * 128;
    const float* bsp[4] = {b0, b1, b2, b3};
#pragma unroll
    for (int j = 0; j < 4; j++) {
        const int gn = n0 + wn + j * 16 + col;
        const int o  = gn & 1023;
        float bv = 0.f;
#pragma unroll
        for (int c = 0; c < 4; c++)
            bv += d_stab[comp * 4 + c] * bsp[comp ^ c][o];
#pragma unroll
        for (int i = 0; i < 8; i++) {
            const int gmb = m0 + wm + i * 16 + rquad;
#pragma unroll
            for (int r = 0; r < 4; r++)
                C[(size_t)(gmb + r) * NDIM + gn] = flip * acc[i][j][r] + bv;
        }
    }
}

// ---------------- fp32 fallback (only if ws too small) ----------------
__global__ void fallback_kernel(const float* __restrict__ x,
                                const float* __restrict__ W0, const float* __restrict__ W1,
                                const float* __restrict__ W2, const float* __restrict__ W3,
                                const float* __restrict__ b0, const float* __restrict__ b1,
                                const float* __restrict__ b2, const float* __restrict__ b3,
                                float* __restrict__ out) {
    int idx = blockIdx.x * 256 + threadIdx.x;   // 16M outputs
    int m = idx >> 12, n = idx & 4095;
    int comp = n >> 10, o = n & 1023;
    const float* Ws[4] = {W0, W1, W2, W3};
    const float* bs[4] = {b0, b1, b2, b3};
    float acc = 0.f;
    for (int c = 0; c < 4; c++) {
        int t = comp * 4 + c;
        const float* wr = Ws[d_qtab[t]] + (size_t)o * 1024;
        const float* xr = x + (size_t)m * 4096 + c * 1024;
        float s = d_stab[t];
        float dot = 0.f;
        for (int i = 0; i < 1024; i += 4) {
            float4 wv = *(const float4*)(wr + i);
            float4 xv = *(const float4*)(xr + i);
            dot += wv.x * xv.x + wv.y * xv.y + wv.z * xv.z + wv.w * xv.w;
        }
        acc += s * dot + s * bs[d_qtab[t]][o];
    }
    out[idx] = acc;
}

// ---------------- launch ----------------
extern "C" void kernel_launch(void* const* d_in, const int* in_sizes, int n_in,
                              void* d_out, int out_size, void* d_ws, size_t ws_size,
                              hipStream_t stream) {
    const float* x = (const float*)d_in[0];
    const float* W[4];
    const float* b[4];
    int wi = 0, bi = 0;
    for (int i = 1; i < n_in && i < 9; i++) {
        if (in_sizes[i] > 4096) { if (wi < 4) W[wi++] = (const float*)d_in[i]; }
        else                    { if (bi < 4) b[bi++] = (const float*)d_in[i]; }
    }
    float* out = (float*)d_out;

    const size_t xh_elems = (size_t)MDIM * KDIM;        // 16M fp16 = 32 MB
    const size_t wh_elems = (size_t)4 * 1024 * 1024;    // 4M fp16 = 8 MB
    const size_t needed = (xh_elems + wh_elems) * 2;

    if (ws_size < needed) {
        fallback_kernel<<<(MDIM * NDIM) / 256, 256, 0, stream>>>(
            x, W[0], W[1], W[2], W[3], b[0], b[1], b[2], b[3], out);
        return;
    }

    _Float16* xh = (_Float16*)d_ws;
    _Float16* Wh = xh + xh_elems;

    prepass_kernel<<<8192 + 2048, 256, 0, stream>>>(x, W[0], W[1], W[2], W[3], xh, Wh);
    gemm_kernel<<<(MDIM / 256) * (NDIM / 256), 512, 0, stream>>>(
        xh, Wh, b[0], b[1], b[2], b[3], out);
}